// Round 19
// baseline (203.560 us; speedup 1.0000x reference)
//
#include <hip/hip_runtime.h>

typedef unsigned int u32;
typedef unsigned short u16;

#define NTOK 131072
#define DIMS 1024
#define NT   256

using bf16x8 = __attribute__((ext_vector_type(8))) short;
using f32x4  = __attribute__((ext_vector_type(4))) float;

// d_ws layout:
//   [0, 1MB)        Bf : bf16[2][32][64][16][8]; slice (p,ks) = 16KB;
//                   within slice: L*128 + slot*8 shorts, slot = n ^ (L&15)
//   [1MB, +1KB)     Sv : float[256]   per-tile nonzero count (slow path)
//   [1MB+1KB, ..)   flags : int[256]  per-tile "sig has exact zero" flag
#define BF_OFF   0
#define SV_OFF   (1 << 20)
#define FLAG_OFF ((1 << 20) + 1024)

// dist = Su + Sv - dot(a,b) - dot(u,v)  [R13-verified, exact]
// if sig has NO exact zeros: dist = 1024 - dot(a,b) exactly (any x).
__device__ __forceinline__ short sgnbf(float v) {
    return v > 0.f ? (short)0x3F80 : (v < 0.f ? (short)0xBF80 : (short)0);
}
__device__ __forceinline__ short absbf(float v) {
    return v != 0.f ? (short)0x3F80 : (short)0;
}

// ---------------------------------------------------------------------------
// Kernel A: B-fragments (bf16 sign/abs planes) in MFMA layout, slot-swizzled.
// (unchanged since R14 — bit-exact verified)
// ---------------------------------------------------------------------------
__global__ void sig_kernel(const float* __restrict__ base,
                           const float* __restrict__ deltas,
                           short* __restrict__ Bf,
                           float* __restrict__ Sv,
                           int* __restrict__ flags)
{
    const int t  = blockIdx.x;
    const int l  = threadIdx.x;
    const int ks = l >> 1;
    int nz = 0, zany = 0;
    #pragma unroll
    for (int gh = 0; gh < 2; ++gh) {
        const int g = (l & 1) * 2 + gh;
        bf16x8 a8, u8;
        #pragma unroll
        for (int j = 0; j < 8; ++j) {
            const int d  = ks * 32 + g * 8 + j;
            const float b  = base[d];
            const float dl = (t > 0) ? deltas[(size_t)(t - 1) * DIMS + d] : 0.f;
            const float s  = (dl != 0.f) ? dl : b;
            a8[j] = sgnbf(s);
            u8[j] = absbf(s);
            nz   += (s != 0.f) ? 1 : 0;
            zany |= (s == 0.f) ? 1 : 0;
        }
        const int L    = g * 16 + (t & 15);
        const int n    = t >> 4;
        const int slot = n ^ (t & 15);
        const size_t off = (size_t)L * 128 + slot * 8;
        *(bf16x8*)(Bf + (((size_t)0 * 32 + ks) << 13) + off) = a8;
        *(bf16x8*)(Bf + (((size_t)1 * 32 + ks) << 13) + off) = u8;
    }
    #pragma unroll
    for (int off = 1; off < 64; off <<= 1) nz += __shfl_xor(nz, off);
    const bool za = __any(zany != 0);
    if (l == 0) { Sv[t] = (float)nz; flags[t] = za ? 1 : 0; }
}

// ---------------------------------------------------------------------------
// Kernel B: producer/consumer MFMA dist (R19). 384 thr = 6 waves:
// waves 0-3 = CONSUMERS (32 tokens each, 2 m-frags; MFMA + ds_read only;
// their only VMEM is issuing the L2-hot B-DMA, drained by their own
// vmcnt(0) under their MFMA phase). Waves 4-5 = PRODUCERS: coalesced x
// loads (3-deep, pure-x vmcnt FIFO), sign-convert in reg, ds_write the
// bf16 A-plane. Producers' HBM waits overlap consumers' compute inside
// the block -> memory duty decoupled from blocks/CU (R18 diagnosis).
// BK=32, 32 phases, raw s_barrier + role-specific waits.
// Fragment mappings identical to R13/R17 (bit-exact verified).
// Slow path (sig exact zeros, ~never): synchronous __syncthreads loop.
// ---------------------------------------------------------------------------
__global__ __launch_bounds__(384)
void dist_kernel(const float* __restrict__ x,
                 const short* __restrict__ Bf,
                 const float* __restrict__ Sv,
                 const int* __restrict__ flags,
                 float* __restrict__ idx_out,
                 float* __restrict__ dist_out)
{
    __shared__ short lds_b[2][8192];   // 32 KB: B slice double buffer
    __shared__ short lds_a[2][4096];   // 16 KB: A (x sign-plane) double buffer

    const int lane = threadIdx.x & 63;
    const int w    = threadIdx.x >> 6;        // 0..5
    const int bid  = blockIdx.x;
    const int mrow = lane & 15;
    const int g    = lane >> 4;

    const int ff = flags[lane] | flags[64 + lane] | flags[128 + lane] | flags[192 + lane];
    const bool sigz = __any(ff != 0);

    const int tok0 = bid * 128 + (w < 4 ? w * 32 : 0);

    f32x4 acc0[16], acc1[16];
    #pragma unroll
    for (int n = 0; n < 16; ++n) {
        acc0[n] = (f32x4){0.f, 0.f, 0.f, 0.f};
        acc1[n] = (f32x4){0.f, 0.f, 0.f, 0.f};
    }
    int nz0 = 0, nz1 = 0;

    // consumer: issue this wave's quarter of B slice ks -> lds_b[buf]
    auto BDMA = [&](int buf, int p, int ks) {
        const short* src = Bf + (((size_t)p * 32 + ks) << 13) + w * 2048 + lane * 8;
        #pragma unroll
        for (int i = 0; i < 4; ++i) {
            __builtin_amdgcn_global_load_lds(
                (const __attribute__((address_space(1))) u32*)(src + i * 512),
                (__attribute__((address_space(3))) u32*)(&lds_b[buf][w * 2048 + i * 512]),
                16, 0, 0);
        }
    };

    if (!sigz) {
        if (w < 4) {
            // ========================== CONSUMER ==========================
            BDMA(0, 0, 0);
            asm volatile("s_waitcnt vmcnt(0)" ::: "memory");
            __builtin_amdgcn_s_barrier();
            __builtin_amdgcn_sched_barrier(0);

            for (int kb = 0; kb < 32; ++kb) {
                if (kb < 31) BDMA((kb + 1) & 1, 0, kb + 1);

                const short* sa = &lds_a[kb & 1][0];
                const short* sb = &lds_b[kb & 1][0];
                const bf16x8 a0 = *(const bf16x8*)(sa + (w * 32 + mrow) * 32 + g * 8);
                const bf16x8 a1 = *(const bf16x8*)(sa + (w * 32 + 16 + mrow) * 32 + g * 8);

                __builtin_amdgcn_s_setprio(1);
                #pragma unroll
                for (int n = 0; n < 16; ++n) {
                    const bf16x8 b = *(const bf16x8*)(sb + lane * 128 + ((n ^ mrow) & 15) * 8);
                    acc0[n] = __builtin_amdgcn_mfma_f32_16x16x32_bf16(a0, b, acc0[n], 0, 0, 0);
                    acc1[n] = __builtin_amdgcn_mfma_f32_16x16x32_bf16(a1, b, acc1[n], 0, 0, 0);
                }
                __builtin_amdgcn_s_setprio(0);

                if (kb < 31) {
                    asm volatile("s_waitcnt vmcnt(0)" ::: "memory");  // B-DMA(kb+1) done
                    __builtin_amdgcn_s_barrier();
                    __builtin_amdgcn_sched_barrier(0);
                }
            }
        } else {
            // ========================== PRODUCER ==========================
            const int j = w - 4;
            const float* xp = x + ((size_t)(bid * 128 + j * 64 + (lane >> 3))) * DIMS
                            + (lane & 7) * 4;

            float4 xb0[8], xb1[8], xb2[8];

            auto XISSUE = [&](float4* dst, int m) {
                #pragma unroll
                for (int i = 0; i < 8; ++i)
                    dst[i] = *(const float4*)(xp + (size_t)i * 8 * DIMS + m * 32);
            };
            auto CONVWRITE = [&](const float4* src, int buf) {
                #pragma unroll
                for (int i = 0; i < 8; ++i) {
                    const u32 lo = (u32)(u16)sgnbf(src[i].x) | ((u32)(u16)sgnbf(src[i].y) << 16);
                    const u32 hi = (u32)(u16)sgnbf(src[i].z) | ((u32)(u16)sgnbf(src[i].w) << 16);
                    uint2 v; v.x = lo; v.y = hi;
                    *(uint2*)&lds_a[buf][(j * 64 + i * 8 + (lane >> 3)) * 32 + (lane & 7) * 4] = v;
                }
            };

            // prologue: x(0)->A(0); x(1),x(2) in flight
            XISSUE(xb0, 0);
            CONVWRITE(xb0, 0);             // compiler inserts the vmcnt wait for xb0
            XISSUE(xb1, 1);
            XISSUE(xb2, 2);
            asm volatile("s_waitcnt lgkmcnt(0)" ::: "memory");
            __builtin_amdgcn_s_barrier();
            __builtin_amdgcn_sched_barrier(0);

            // phases kb = 0..30 (producer does nothing at kb=31)
            #define PPHASE(KB, CUR, TGT) {                                   \
                CONVWRITE(CUR, ((KB) + 1) & 1);                              \
                if ((KB) <= 28) XISSUE(TGT, (KB) + 3);                       \
                asm volatile("s_waitcnt lgkmcnt(0)" ::: "memory");           \
                __builtin_amdgcn_s_barrier();                                \
                __builtin_amdgcn_sched_barrier(0);                           \
            }
            for (int kbb = 0; kbb < 30; kbb += 3) {
                PPHASE(kbb + 0, xb1, xb0)
                PPHASE(kbb + 1, xb2, xb1)
                PPHASE(kbb + 2, xb0, xb2)
            }
            PPHASE(30, xb1, xb0)
            #undef PPHASE
            // kb=31: no work, no barrier (consumers also emit none)
        }
    } else {
        // ================= SLOW PATH (synchronous, 2 planes) =================
        const float* xr0 = x + (size_t)(tok0 + mrow) * DIMS + g * 8;
        const float* xr1 = x + (size_t)(tok0 + 16 + mrow) * DIMS + g * 8;

        for (int p = 0; p < 2; ++p) {
            if (w < 4) BDMA(0, p, 0);
            __syncthreads();
            for (int kb = 0; kb < 32; ++kb) {
                if (w < 4) {
                    if (kb < 31) BDMA((kb + 1) & 1, p, kb + 1);

                    const float4 v00 = *(const float4*)(xr0 + kb * 32);
                    const float4 v01 = *(const float4*)(xr0 + kb * 32 + 4);
                    const float4 v10 = *(const float4*)(xr1 + kb * 32);
                    const float4 v11 = *(const float4*)(xr1 + kb * 32 + 4);

                    bf16x8 f0, f1;
                    #pragma unroll
                    for (int jj = 0; jj < 4; ++jj) {
                        f0[jj]     = p ? absbf(v00[jj]) : sgnbf(v00[jj]);
                        f0[4 + jj] = p ? absbf(v01[jj]) : sgnbf(v01[jj]);
                        f1[jj]     = p ? absbf(v10[jj]) : sgnbf(v10[jj]);
                        f1[4 + jj] = p ? absbf(v11[jj]) : sgnbf(v11[jj]);
                    }
                    if (p == 1) {
                        #pragma unroll
                        for (int jj = 0; jj < 4; ++jj) {
                            nz0 += (v00[jj] != 0.f) + (v01[jj] != 0.f);
                            nz1 += (v10[jj] != 0.f) + (v11[jj] != 0.f);
                        }
                    }

                    const short* sb = &lds_b[kb & 1][0];
                    #pragma unroll
                    for (int n = 0; n < 16; ++n) {
                        const bf16x8 b = *(const bf16x8*)(sb + lane * 128 + ((n ^ mrow) & 15) * 8);
                        acc0[n] = __builtin_amdgcn_mfma_f32_16x16x32_bf16(f0, b, acc0[n], 0, 0, 0);
                        acc1[n] = __builtin_amdgcn_mfma_f32_16x16x32_bf16(f1, b, acc1[n], 0, 0, 0);
                    }
                }
                __syncthreads();
            }
        }
    }

    // ---- epilogue (consumers only; R14-verified) ----
    if (w < 4) {
        float su0r[4], su1r[4];
        if (sigz) {
            nz0 += __shfl_xor(nz0, 16); nz0 += __shfl_xor(nz0, 32);
            nz1 += __shfl_xor(nz1, 16); nz1 += __shfl_xor(nz1, 32);
            const float s0 = (float)nz0, s1 = (float)nz1;
            #pragma unroll
            for (int r = 0; r < 4; ++r) {
                su0r[r] = __shfl(s0, g * 4 + r);
                su1r[r] = __shfl(s1, g * 4 + r);
            }
        }

        int key0[4] = {0x7fffffff,0x7fffffff,0x7fffffff,0x7fffffff};
        int key1[4] = {0x7fffffff,0x7fffffff,0x7fffffff,0x7fffffff};
        #pragma unroll
        for (int n = 0; n < 16; ++n) {
            const int tile = n * 16 + mrow;
            const float svv = sigz ? Sv[tile] : 0.f;
            #pragma unroll
            for (int r = 0; r < 4; ++r) {
                const float dv0 = sigz ? (su0r[r] + svv - acc0[n][r]) : (1024.f - acc0[n][r]);
                const float dv1 = sigz ? (su1r[r] + svv - acc1[n][r]) : (1024.f - acc1[n][r]);
                dist_out[(size_t)(tok0 + g * 4 + r) * NT + tile]      = dv0;
                dist_out[(size_t)(tok0 + 16 + g * 4 + r) * NT + tile] = dv1;
                key0[r] = min(key0[r], ((int)dv0 << 8) | tile);
                key1[r] = min(key1[r], ((int)dv1 << 8) | tile);
            }
        }
        #pragma unroll
        for (int off = 1; off < 16; off <<= 1) {
            #pragma unroll
            for (int r = 0; r < 4; ++r) {
                key0[r] = min(key0[r], __shfl_xor(key0[r], off));
                key1[r] = min(key1[r], __shfl_xor(key1[r], off));
            }
        }
        if (mrow == 0) {
            #pragma unroll
            for (int r = 0; r < 4; ++r) {
                idx_out[tok0 + g * 4 + r]      = (float)(key0[r] & 255);
                idx_out[tok0 + 16 + g * 4 + r] = (float)(key1[r] & 255);
            }
        }
    }
}

extern "C" void kernel_launch(void* const* d_in, const int* in_sizes, int n_in,
                              void* d_out, int out_size, void* d_ws, size_t ws_size,
                              hipStream_t stream)
{
    const float* x      = (const float*)d_in[0];
    const float* base   = (const float*)d_in[1];
    const float* deltas = (const float*)d_in[2];

    short* Bf  = (short*)((char*)d_ws + BF_OFF);
    float* Sv  = (float*)((char*)d_ws + SV_OFF);
    int* flags = (int*)((char*)d_ws + FLAG_OFF);

    float* idx_out  = (float*)d_out;                 // N floats (tile indices)
    float* dist_out = idx_out + NTOK;                // N*T floats

    sig_kernel<<<NT, 64, 0, stream>>>(base, deltas, Bf, Sv, flags);
    dist_kernel<<<NTOK / 128, 384, 0, stream>>>(x, Bf, Sv, flags, idx_out, dist_out);
}

// Round 20
// 200.068 us; speedup vs baseline: 1.0175x; 1.0175x over previous
//
#include <hip/hip_runtime.h>

typedef unsigned int u32;
typedef unsigned long long u64;

#define NTOK 131072
#define DIMS 1024
#define NT   256

using f32x4 = __attribute__((ext_vector_type(4))) float;

// d_ws layout:
//   [0, 557056)     Bf8 : fp8 B-fragments, fragment-image, padded rows.
//                   plane p (0=sign,1=abs), K-quarter kq, row (ks_in*64+L),
//                   slot s: byte = p*278528 + kq*69632 + (ks_in*64+L)*136 + s*8
//                   frag (t, ks, L): n=t>>4, slot=n^(t&15), elems j=0..7 of
//                   plane_p(sig[t][ks*32 + (L>>4)*8 + j]) as e4m3 {0,±1}.
//   [1MB, +1KB)     Sv   : float[256] per-tile nonzero count (slow path)
//   [1MB+1KB, ..)   flags: int[256]   per-tile "sig has exact zero"
#define BF_OFF   0
#define PL_STR   278528          // plane stride  (4 * 69632)
#define KQ_STR   69632           // K-quarter slice (8*64 rows * 136 B)
#define SV_OFF   (1 << 20)
#define FLAG_OFF ((1 << 20) + 1024)

// dist = Su + Sv - dot(a,b) - dot(u,v)  [R13-verified, exact]
// if sig has NO exact zeros: dist = 1024 - dot(a,b) exactly (any x).
__device__ __forceinline__ u32 sgn8(float v) {   // e4m3: 1.0=0x38, -1.0=0xB8
    return v > 0.f ? 0x38u : (v < 0.f ? 0xB8u : 0u);
}
__device__ __forceinline__ u32 abs8(float v) {
    return v != 0.f ? 0x38u : 0u;
}
__device__ __forceinline__ u64 pack8(float4 a, float4 b, int p) {
    u32 lo, hi;
    if (p == 0) {
        lo = sgn8(a.x) | (sgn8(a.y) << 8) | (sgn8(a.z) << 16) | (sgn8(a.w) << 24);
        hi = sgn8(b.x) | (sgn8(b.y) << 8) | (sgn8(b.z) << 16) | (sgn8(b.w) << 24);
    } else {
        lo = abs8(a.x) | (abs8(a.y) << 8) | (abs8(a.z) << 16) | (abs8(a.w) << 24);
        hi = abs8(b.x) | (abs8(b.y) << 8) | (abs8(b.z) << 16) | (abs8(b.w) << 24);
    }
    return (u64)lo | ((u64)hi << 32);
}

// ---------------------------------------------------------------------------
// Kernel A: fp8 B-fragments in padded fragment-image layout (index algebra
// identical to the bf16 bit-exact-verified table; only elem width changed).
// ---------------------------------------------------------------------------
__global__ void sig_kernel(const float* __restrict__ base,
                           const float* __restrict__ deltas,
                           char* __restrict__ Bf8,
                           float* __restrict__ Sv,
                           int* __restrict__ flags)
{
    const int t  = blockIdx.x;
    const int l  = threadIdx.x;
    const int ks = l >> 1;
    int nz = 0, zany = 0;
    #pragma unroll
    for (int gh = 0; gh < 2; ++gh) {
        const int g = (l & 1) * 2 + gh;
        float sv[8];
        #pragma unroll
        for (int j = 0; j < 8; ++j) {
            const int d  = ks * 32 + g * 8 + j;
            const float b  = base[d];
            const float dl = (t > 0) ? deltas[(size_t)(t - 1) * DIMS + d] : 0.f;
            const float s  = (dl != 0.f) ? dl : b;
            sv[j] = s;
            nz   += (s != 0.f) ? 1 : 0;
            zany |= (s == 0.f) ? 1 : 0;
        }
        float4 v0, v1;
        v0.x = sv[0]; v0.y = sv[1]; v0.z = sv[2]; v0.w = sv[3];
        v1.x = sv[4]; v1.y = sv[5]; v1.z = sv[6]; v1.w = sv[7];
        const u64 pa = pack8(v0, v1, 0);
        const u64 pu = pack8(v0, v1, 1);

        const int L    = g * 16 + (t & 15);
        const int n    = t >> 4;
        const int slot = (n ^ (t & 15)) & 15;
        const size_t off = (size_t)(ks >> 3) * KQ_STR
                         + (size_t)((ks & 7) * 64 + L) * 136 + slot * 8;
        *(u64*)(Bf8 + off)           = pa;
        *(u64*)(Bf8 + PL_STR + off)  = pu;
    }
    #pragma unroll
    for (int off = 1; off < 64; off <<= 1) nz += __shfl_xor(nz, off);
    const bool za = __any(zany != 0);
    if (l == 0) { Sv[t] = (float)nz; flags[t] = za ? 1 : 0; }
}

// ---------------------------------------------------------------------------
// Kernel B: fp8 MFMA dist, barrier-free steady state (R20).
// 4 waves, 128 tokens/block (32/wave, 2 m-frags — R17-verified geometry).
// Whole K-quarter of B (68 KB, padded rows vs bank aliasing) staged ONCE
// into single-buffer LDS; then a long unsynchronized streaming phase:
// per ks: 4 coalesced x float4 loads (1-deep prefetch) -> fp8 pack ->
// 16 ds_read_b64 + 32 MFMA fp8. Only 2 barriers per quarter (8 total) —
// waves decouple from each other's HBM waits (R19 diagnosis: per-phase
// barriers re-couple every wave to the HBM feed 16-32x per kernel).
// Slow path (sig has exact zeros, ~never): second pass over abs-plane.
// ---------------------------------------------------------------------------
__global__ __launch_bounds__(256, 2)
void dist_kernel(const float* __restrict__ x,
                 const char* __restrict__ Bf8,
                 const float* __restrict__ Sv,
                 const int* __restrict__ flags,
                 float* __restrict__ idx_out,
                 float* __restrict__ dist_out)
{
    __shared__ u64 ldsb[KQ_STR / 8];   // 69632 B single buffer

    const int lane = threadIdx.x & 63;
    const int w    = threadIdx.x >> 6;
    const int tok0 = blockIdx.x * 128 + w * 32;
    const int mrow = lane & 15;
    const int g    = lane >> 4;

    const int ff = flags[lane] | flags[64 + lane] | flags[128 + lane] | flags[192 + lane];
    const bool sigz = __any(ff != 0);

    const float* __restrict__ xr0 = x + (size_t)(tok0 + mrow) * DIMS + g * 8;
    const float* __restrict__ xr1 = x + (size_t)(tok0 + 16 + mrow) * DIMS + g * 8;

    f32x4 acc0[16], acc1[16];
    #pragma unroll
    for (int n = 0; n < 16; ++n) {
        acc0[n] = (f32x4){0.f, 0.f, 0.f, 0.f};
        acc1[n] = (f32x4){0.f, 0.f, 0.f, 0.f};
    }

    // reg-staged copy of one 68 KB K-quarter slice (wave w: bytes [w*17408,+17408))
    auto STAGE = [&](int p, int kq) {
        const char* src = Bf8 + (size_t)p * PL_STR + (size_t)kq * KQ_STR
                        + w * 17408 + lane * 16;
        char* dst = (char*)ldsb + w * 17408 + lane * 16;
        #pragma unroll
        for (int i0 = 0; i0 < 17; i0 += 5) {
            uint4 tmp[5];
            #pragma unroll
            for (int i = 0; i < 5; ++i)
                if (i0 + i < 17) tmp[i] = *(const uint4*)(src + (i0 + i) * 1024);
            #pragma unroll
            for (int i = 0; i < 5; ++i)
                if (i0 + i < 17) *(uint4*)(dst + (i0 + i) * 1024) = tmp[i];
        }
    };

    int nz0 = 0, nz1 = 0;
    const int nplanes = sigz ? 2 : 1;

    for (int p = 0; p < nplanes; ++p) {
        for (int kq = 0; kq < 4; ++kq) {
            __syncthreads();            // previous phase's LDS reads complete
            STAGE(p, kq);
            __syncthreads();            // staged slice visible to all waves

            // -------- barrier-free streaming over 8 k-steps --------
            float4 c0 = *(const float4*)(xr0 + kq * 256);
            float4 c1 = *(const float4*)(xr0 + kq * 256 + 4);
            float4 c2 = *(const float4*)(xr1 + kq * 256);
            float4 c3 = *(const float4*)(xr1 + kq * 256 + 4);

            for (int ks = 0; ks < 8; ++ks) {
                float4 n0, n1, n2, n3;
                if (ks < 7) {
                    const int o = kq * 256 + (ks + 1) * 32;
                    n0 = *(const float4*)(xr0 + o); n1 = *(const float4*)(xr0 + o + 4);
                    n2 = *(const float4*)(xr1 + o); n3 = *(const float4*)(xr1 + o + 4);
                }

                const u64 a0 = pack8(c0, c1, p);
                const u64 a1 = pack8(c2, c3, p);
                if (p == 1) {
                    nz0 += (c0.x!=0.f)+(c0.y!=0.f)+(c0.z!=0.f)+(c0.w!=0.f)
                         + (c1.x!=0.f)+(c1.y!=0.f)+(c1.z!=0.f)+(c1.w!=0.f);
                    nz1 += (c2.x!=0.f)+(c2.y!=0.f)+(c2.z!=0.f)+(c2.w!=0.f)
                         + (c3.x!=0.f)+(c3.y!=0.f)+(c3.z!=0.f)+(c3.w!=0.f);
                }

                const char* rowb = (const char*)ldsb + (size_t)(ks * 64 + lane) * 136;
                __builtin_amdgcn_s_setprio(1);
                #pragma unroll
                for (int n = 0; n < 16; ++n) {
                    const u64 b = *(const u64*)(rowb + (((n ^ mrow) & 15) * 8));
                    acc0[n] = __builtin_amdgcn_mfma_f32_16x16x32_fp8_fp8(
                        (long)a0, (long)b, acc0[n], 0, 0, 0);
                    acc1[n] = __builtin_amdgcn_mfma_f32_16x16x32_fp8_fp8(
                        (long)a1, (long)b, acc1[n], 0, 0, 0);
                }
                __builtin_amdgcn_s_setprio(0);

                c0 = n0; c1 = n1; c2 = n2; c3 = n3;
            }
        }
    }

    // ---- epilogue (R14/R17-verified geometry) ----
    float su0r[4], su1r[4];
    if (sigz) {
        nz0 += __shfl_xor(nz0, 16); nz0 += __shfl_xor(nz0, 32);
        nz1 += __shfl_xor(nz1, 16); nz1 += __shfl_xor(nz1, 32);
        const float s0 = (float)nz0, s1 = (float)nz1;
        #pragma unroll
        for (int r = 0; r < 4; ++r) {
            su0r[r] = __shfl(s0, g * 4 + r);
            su1r[r] = __shfl(s1, g * 4 + r);
        }
    }

    int key0[4] = {0x7fffffff,0x7fffffff,0x7fffffff,0x7fffffff};
    int key1[4] = {0x7fffffff,0x7fffffff,0x7fffffff,0x7fffffff};
    #pragma unroll
    for (int n = 0; n < 16; ++n) {
        const int tile = n * 16 + mrow;
        const float svv = sigz ? Sv[tile] : 0.f;
        #pragma unroll
        for (int r = 0; r < 4; ++r) {
            const float dv0 = sigz ? (su0r[r] + svv - acc0[n][r]) : (1024.f - acc0[n][r]);
            const float dv1 = sigz ? (su1r[r] + svv - acc1[n][r]) : (1024.f - acc1[n][r]);
            dist_out[(size_t)(tok0 + g * 4 + r) * NT + tile]      = dv0;
            dist_out[(size_t)(tok0 + 16 + g * 4 + r) * NT + tile] = dv1;
            key0[r] = min(key0[r], ((int)dv0 << 8) | tile);
            key1[r] = min(key1[r], ((int)dv1 << 8) | tile);
        }
    }
    #pragma unroll
    for (int off = 1; off < 16; off <<= 1) {
        #pragma unroll
        for (int r = 0; r < 4; ++r) {
            key0[r] = min(key0[r], __shfl_xor(key0[r], off));
            key1[r] = min(key1[r], __shfl_xor(key1[r], off));
        }
    }
    if (mrow == 0) {
        #pragma unroll
        for (int r = 0; r < 4; ++r) {
            idx_out[tok0 + g * 4 + r]      = (float)(key0[r] & 255);
            idx_out[tok0 + 16 + g * 4 + r] = (float)(key1[r] & 255);
        }
    }
}

extern "C" void kernel_launch(void* const* d_in, const int* in_sizes, int n_in,
                              void* d_out, int out_size, void* d_ws, size_t ws_size,
                              hipStream_t stream)
{
    const float* x      = (const float*)d_in[0];
    const float* base   = (const float*)d_in[1];
    const float* deltas = (const float*)d_in[2];

    char*  Bf8   = (char*)d_ws + BF_OFF;
    float* Sv    = (float*)((char*)d_ws + SV_OFF);
    int*   flags = (int*)((char*)d_ws + FLAG_OFF);

    float* idx_out  = (float*)d_out;                 // N floats (tile indices)
    float* dist_out = idx_out + NTOK;                // N*T floats

    sig_kernel<<<NT, 64, 0, stream>>>(base, deltas, Bf8, Sv, flags);
    dist_kernel<<<NTOK / 128, 256, 0, stream>>>(x, Bf8, Sv, flags, idx_out, dist_out);
}